// Round 1
// baseline (377.774 us; speedup 1.0000x reference)
//
#include <hip/hip_runtime.h>

typedef unsigned short u16;
typedef __bf16 bf16x8 __attribute__((ext_vector_type(8)));
typedef __bf16 bf16x2 __attribute__((ext_vector_type(2)));
typedef float f32x4 __attribute__((ext_vector_type(4)));
typedef float f32x16 __attribute__((ext_vector_type(16)));
typedef unsigned int uint2v __attribute__((ext_vector_type(2)));

#define DEV static __device__ __forceinline__

DEV u16 f2bf(float f) { __bf16 h = (__bf16)f; return __builtin_bit_cast(u16, h); }
DEV unsigned pk2(float a, float b) {
    bf16x2 t; t[0] = (__bf16)a; t[1] = (__bf16)b;
    return __builtin_bit_cast(unsigned, t);
}

#define GLD16(gp, lp)                                                          \
    __builtin_amdgcn_global_load_lds(                                          \
        (const __attribute__((address_space(1))) void*)(gp),                   \
        (__attribute__((address_space(3))) void*)(lp), 16, 0, 0)

// ---------------------------------------------------------------- fp32->bf16
__global__ void cvt_bf16(const float* __restrict__ src, u16* __restrict__ dst, int n8) {
    int i = blockIdx.x * 256 + threadIdx.x;
    if (i >= n8) return;
    const float4* s = (const float4*)src;
    float4 a = s[2 * i], b = s[2 * i + 1];
    uint4 o;
    o.x = pk2(a.x, a.y); o.y = pk2(a.z, a.w);
    o.z = pk2(b.x, b.y); o.w = pk2(b.z, b.w);
    ((uint4*)dst)[i] = o;
}

// ------------------------------------------------- GEMM: C[M,N] = A[M,K]*B[N,K]^T
// M=8192 (tokens), N=1024, K=1024. 128x128 tile, BK=64, 4 waves (2x2 of 64x64).
// LDS rows are 128B with 16B-chunk XOR swizzle: LDS[r][c] holds global chunk c^(r&7).
// EPI 0: bf16 scatter to [B,H,S,Dh];  EPI 1: fp32 row-major + done.
template <int EPI>
__global__ __launch_bounds__(256) void gemm_bt(const u16* __restrict__ A,
                                               const u16* __restrict__ Bw,
                                               const float* __restrict__ bias,
                                               u16* __restrict__ obf,
                                               float* __restrict__ of32) {
    __shared__ u16 Asm[128 * 64];
    __shared__ u16 Bsm[128 * 64];
    const int tid = threadIdx.x, lane = tid & 63, wave = tid >> 6;
    const int m0 = blockIdx.y * 128, n0 = blockIdx.x * 128;
    const int wr = wave >> 1, wc = wave & 1;
    const int srow = lane >> 3;                 // 0..7 row-within-chunk
    const int scol = (lane & 7) ^ srow;         // pre-swizzled source chunk
    f32x4 acc[4][4] = {};

    for (int kt = 0; kt < 16; ++kt) {
        __syncthreads();
#pragma unroll
        for (int i = 0; i < 4; ++i) {
            int ch = wave * 4 + i;              // 16 chunks of 1KB per tile
            int r = ch * 8 + srow;              // tile row 0..127
            GLD16(A + (size_t)(m0 + r) * 1024 + kt * 64 + scol * 8, Asm + ch * 512);
            GLD16(Bw + (size_t)(n0 + r) * 1024 + kt * 64 + scol * 8, Bsm + ch * 512);
        }
        asm volatile("s_waitcnt vmcnt(0)" ::: "memory");
        __syncthreads();
#pragma unroll
        for (int ks = 0; ks < 2; ++ks) {
            bf16x8 af[4], bf[4];
#pragma unroll
            for (int t = 0; t < 4; ++t) {
                int ra = wr * 64 + t * 16 + (lane & 15);
                int ca = (ks * 4 + (lane >> 4)) ^ (ra & 7);
                af[t] = *(const bf16x8*)(Asm + ra * 64 + ca * 8);
                int rb = wc * 64 + t * 16 + (lane & 15);
                int cb = (ks * 4 + (lane >> 4)) ^ (rb & 7);
                bf[t] = *(const bf16x8*)(Bsm + rb * 64 + cb * 8);
            }
#pragma unroll
            for (int mi = 0; mi < 4; ++mi)
#pragma unroll
                for (int ni = 0; ni < 4; ++ni)
                    acc[mi][ni] = __builtin_amdgcn_mfma_f32_16x16x32_bf16(
                        af[mi], bf[ni], acc[mi][ni], 0, 0, 0);
        }
    }
    // epilogue: C/D 16x16 layout: col = lane&15, row = (lane>>4)*4 + reg
    const int rl = (lane >> 4) * 4, cl = lane & 15;
#pragma unroll
    for (int ni = 0; ni < 4; ++ni) {
        int gn = n0 + wc * 64 + ni * 16 + cl;
        float bv = bias[gn];
#pragma unroll
        for (int mi = 0; mi < 4; ++mi) {
#pragma unroll
            for (int r = 0; r < 4; ++r) {
                int gm = m0 + wr * 64 + mi * 16 + rl + r;
                float v = acc[mi][ni][r] + bv;
                if (EPI == 0) {
                    int b = gm >> 11, s = gm & 2047, h = gn >> 6, d = gn & 63;
                    obf[(((size_t)(b * 16 + h)) * 2048 + s) * 64 + d] = f2bf(v);
                } else {
                    of32[(size_t)gm * 1024 + gn] = v;
                }
            }
        }
    }
}

// ----------------------------------------- V [BH][S][64] -> VT [BH][64][S]
__global__ __launch_bounds__(256) void vtrans(const u16* __restrict__ V,
                                              u16* __restrict__ VT) {
    __shared__ u16 t[64 * 72];                  // 144B row stride (16B-aligned)
    const int bh = blockIdx.y, s0 = blockIdx.x * 64;
    const int tid = threadIdx.x;
    const u16* src = V + ((size_t)bh * 2048 + s0) * 64;
#pragma unroll
    for (int p = 0; p < 2; ++p) {
        int si = p * 256 + tid;
        int r = si >> 3, sl = si & 7;
        *(uint4*)(t + r * 72 + sl * 8) = *(const uint4*)(src + r * 64 + sl * 8);
    }
    __syncthreads();
    u16* dst = VT + (size_t)bh * 64 * 2048;
#pragma unroll
    for (int p = 0; p < 2; ++p) {
        int sj = p * 256 + tid;
        int d = sj >> 3, os = (sj & 7) * 8;
        u16 tmp[8];
#pragma unroll
        for (int j = 0; j < 8; ++j) tmp[j] = t[(os + j) * 72 + d];
        *(uint4*)(dst + (size_t)d * 2048 + s0 + os) = *(uint4*)tmp;
    }
}

// ------------------------------------------------------------ flash attention
// grid (S/128, B*H), 256 thr. Wave handles 32 q-rows. KV tile = 64, single-buffer.
// Swapped QK^T: mfma(K,Q) -> lane holds scores for q = lane&31 (softmax lane-local).
// P->A-frag redistribution via permlane32_swap (T12). PV B-operand from VT rows.
__global__ __launch_bounds__(256) void attn_fwd(const u16* __restrict__ Q,
                                                const u16* __restrict__ K,
                                                const u16* __restrict__ VT,
                                                u16* __restrict__ ctx) {
    __shared__ u16 Ksm[64 * 64];
    __shared__ u16 Vsm[64 * 64];
    const int tid = threadIdx.x, lane = tid & 63, wave = tid >> 6;
    const int bh = blockIdx.y;
    const int q0 = blockIdx.x * 128 + wave * 32;
    const int ql = lane & 31, hi = lane >> 5;
    const int srow = lane >> 3, scol = (lane & 7) ^ srow;

    // Q B-operand frags: lane holds Q[q0+ql][d16*16 + hi*8 + j]
    const u16* Qb = Q + ((size_t)bh * 2048 + q0 + ql) * 64 + hi * 8;
    bf16x8 qf[4];
#pragma unroll
    for (int d16 = 0; d16 < 4; ++d16) qf[d16] = *(const bf16x8*)(Qb + d16 * 16);

    const u16* Kb = K + (size_t)bh * 2048 * 64;
    const u16* Vb = VT + (size_t)bh * 64 * 2048;

    f32x16 o0 = {}, o1 = {};
    float m = -1e30f, lsum = 0.f;
    const float C = 0.18033688011112042f;       // log2(e)/sqrt(64)

    for (int kb = 0; kb < 2048; kb += 64) {
        __syncthreads();
#pragma unroll
        for (int i = 0; i < 2; ++i) {
            int ch = wave * 2 + i;
            int r = ch * 8 + srow;
            GLD16(Kb + (size_t)(kb + r) * 64 + scol * 8, Ksm + ch * 512);
            GLD16(Vb + (size_t)r * 2048 + kb + scol * 8, Vsm + ch * 512);
        }
        asm volatile("s_waitcnt vmcnt(0)" ::: "memory");
        __syncthreads();

        // QK^T (swapped): sa[t] rows = keys t*32.., cols = q
        f32x16 sa[2] = {};
#pragma unroll
        for (int t = 0; t < 2; ++t)
#pragma unroll
            for (int d16 = 0; d16 < 4; ++d16) {
                int r = t * 32 + ql;
                int c = (d16 * 2 + hi) ^ (r & 7);
                bf16x8 kf = *(const bf16x8*)(Ksm + r * 64 + c * 8);
                sa[t] = __builtin_amdgcn_mfma_f32_32x32x16_bf16(kf, qf[d16], sa[t], 0, 0, 0);
            }

        // online softmax for q = ql (32 k-vals in-lane, partner lane is l^32)
        float tmax = -1e30f;
#pragma unroll
        for (int t = 0; t < 2; ++t)
#pragma unroll
            for (int r = 0; r < 16; ++r) tmax = fmaxf(tmax, sa[t][r]);
        tmax = fmaxf(tmax, __shfl_xor(tmax, 32));
        float mn = fmaxf(m, tmax);
        float f = exp2f((m - mn) * C);
        float p[32]; float ps = 0.f;
#pragma unroll
        for (int t = 0; t < 2; ++t)
#pragma unroll
            for (int r = 0; r < 16; ++r) {
                float e = exp2f((sa[t][r] - mn) * C);
                p[t * 16 + r] = e; ps += e;
            }
        ps += __shfl_xor(ps, 32);
        lsum = lsum * f + ps;
        m = mn;

        // rescale O (O rows q' = crow(r,hi); broadcast f from lane holding q')
#pragma unroll
        for (int r = 0; r < 16; ++r) {
            int crow = (r & 3) + 8 * (r >> 2) + 4 * hi;
            float fr = __shfl(f, (lane & 32) + crow);
            o0[r] *= fr; o1[r] *= fr;
        }

        // P -> bf16 A-frags via permlane32_swap, then PV
#pragma unroll
        for (int t = 0; t < 2; ++t) {
            unsigned pkv[8];
#pragma unroll
            for (int i2 = 0; i2 < 8; ++i2)
                pkv[i2] = pk2(p[t * 16 + 2 * i2], p[t * 16 + 2 * i2 + 1]);
            uint2v s0 = __builtin_amdgcn_permlane32_swap(pkv[0], pkv[2], false, false);
            uint2v s1 = __builtin_amdgcn_permlane32_swap(pkv[1], pkv[3], false, false);
            uint2v s2 = __builtin_amdgcn_permlane32_swap(pkv[4], pkv[6], false, false);
            uint2v s3 = __builtin_amdgcn_permlane32_swap(pkv[5], pkv[7], false, false);
            uint4 fr0 = {s0[0], s1[0], s0[1], s1[1]};
            uint4 fr1 = {s2[0], s3[0], s2[1], s3[1]};
            bf16x8 pf[2] = {__builtin_bit_cast(bf16x8, fr0), __builtin_bit_cast(bf16x8, fr1)};
#pragma unroll
            for (int kk = 0; kk < 2; ++kk) {
#pragma unroll
                for (int db = 0; db < 2; ++db) {
                    int dr = db * 32 + ql;
                    int cc = ((t * 2 + kk) * 2 + hi) ^ (dr & 7);
                    bf16x8 vf = *(const bf16x8*)(Vsm + dr * 64 + cc * 8);
                    if (db == 0)
                        o0 = __builtin_amdgcn_mfma_f32_32x32x16_bf16(pf[kk], vf, o0, 0, 0, 0);
                    else
                        o1 = __builtin_amdgcn_mfma_f32_32x32x16_bf16(pf[kk], vf, o1, 0, 0, 0);
                }
            }
        }
    }

    // epilogue: ctx[B,S,H*64] bf16
    float linv = 1.0f / lsum;
    const int b = bh >> 4, h = bh & 15;
#pragma unroll
    for (int r = 0; r < 16; ++r) {
        int crow = (r & 3) + 8 * (r >> 2) + 4 * hi;
        float lr = __shfl(linv, (lane & 32) + crow);
        size_t base = ((size_t)b * 2048 + q0 + crow) * 1024 + h * 64;
        ctx[base + ql] = f2bf(o0[r] * lr);
        ctx[base + 32 + ql] = f2bf(o1[r] * lr);
    }
}

// ---------------------------------------------------------------- launcher
extern "C" void kernel_launch(void* const* d_in, const int* in_sizes, int n_in,
                              void* d_out, int out_size, void* d_ws, size_t ws_size,
                              hipStream_t stream) {
    const float* x  = (const float*)d_in[0];
    const float* Wq = (const float*)d_in[1];
    const float* bq = (const float*)d_in[2];
    const float* Wk = (const float*)d_in[3];
    const float* bk = (const float*)d_in[4];
    const float* Wv = (const float*)d_in[5];
    const float* bv = (const float*)d_in[6];
    const float* Wo = (const float*)d_in[7];
    const float* bo = (const float*)d_in[8];
    float* out = (float*)d_out;

    char* ws = (char*)d_ws;
    u16* xb  = (u16*)(ws);                          // 16 MB (reused as ctx)
    u16* wqb = (u16*)(ws + 16777216);
    u16* wkb = (u16*)(ws + 16777216 + 2097152);
    u16* wvb = (u16*)(ws + 16777216 + 2 * 2097152);
    u16* wob = (u16*)(ws + 16777216 + 3 * 2097152);
    u16* qb  = (u16*)(ws + 25165824);
    u16* kb  = (u16*)(ws + 41943040);
    u16* vb  = (u16*)(ws + 58720256);
    u16* vtb = (u16*)(ws + 75497472);
    u16* ctx = xb;                                   // xb dead after V GEMM

    cvt_bf16<<<4096, 256, 0, stream>>>(x, xb, 1048576);
    cvt_bf16<<<512, 256, 0, stream>>>(Wq, wqb, 131072);
    cvt_bf16<<<512, 256, 0, stream>>>(Wk, wkb, 131072);
    cvt_bf16<<<512, 256, 0, stream>>>(Wv, wvb, 131072);
    cvt_bf16<<<512, 256, 0, stream>>>(Wo, wob, 131072);

    dim3 gg(8, 64);
    gemm_bt<0><<<gg, 256, 0, stream>>>(xb, wqb, bq, qb, nullptr);
    gemm_bt<0><<<gg, 256, 0, stream>>>(xb, wkb, bk, kb, nullptr);
    gemm_bt<0><<<gg, 256, 0, stream>>>(xb, wvb, bv, vb, nullptr);
    vtrans<<<dim3(32, 64), 256, 0, stream>>>(vb, vtb);
    attn_fwd<<<dim3(16, 64), 256, 0, stream>>>(qb, kb, vtb, ctx);
    gemm_bt<1><<<gg, 256, 0, stream>>>(ctx, wob, bo, nullptr, out);
}

// Round 2
// 356.252 us; speedup vs baseline: 1.0604x; 1.0604x over previous
//
#include <hip/hip_runtime.h>

typedef unsigned short u16;
typedef __bf16 bf16x8 __attribute__((ext_vector_type(8)));
typedef __bf16 bf16x2 __attribute__((ext_vector_type(2)));
typedef float f32x4 __attribute__((ext_vector_type(4)));
typedef float f32x16 __attribute__((ext_vector_type(16)));
typedef unsigned int uint2v __attribute__((ext_vector_type(2)));

#define DEV static __device__ __forceinline__

DEV u16 f2bf(float f) { __bf16 h = (__bf16)f; return __builtin_bit_cast(u16, h); }
DEV unsigned pk2(float a, float b) {
    bf16x2 t; t[0] = (__bf16)a; t[1] = (__bf16)b;
    return __builtin_bit_cast(unsigned, t);
}

#define GLD16(gp, lp)                                                          \
    __builtin_amdgcn_global_load_lds(                                          \
        (const __attribute__((address_space(1))) void*)(gp),                   \
        (__attribute__((address_space(3))) void*)(lp), 16, 0, 0)

// ---------------------------------------------------------------- fp32->bf16
__global__ void cvt_bf16(const float* __restrict__ src, u16* __restrict__ dst, int n8) {
    int i = blockIdx.x * 256 + threadIdx.x;
    if (i >= n8) return;
    const float4* s = (const float4*)src;
    float4 a = s[2 * i], b = s[2 * i + 1];
    uint4 o;
    o.x = pk2(a.x, a.y); o.y = pk2(a.z, a.w);
    o.z = pk2(b.x, b.y); o.w = pk2(b.z, b.w);
    ((uint4*)dst)[i] = o;
}

// 4 weight matrices (1M elems each) in one dispatch: blocks 0..511 -> W0, etc.
__global__ void cvt_bf16_w4(const float* __restrict__ w0, const float* __restrict__ w1,
                            const float* __restrict__ w2, const float* __restrict__ w3,
                            u16* __restrict__ o0, u16* __restrict__ o1,
                            u16* __restrict__ o2, u16* __restrict__ o3) {
    int g = blockIdx.x >> 9;
    const float* src = g == 0 ? w0 : (g == 1 ? w1 : (g == 2 ? w2 : w3));
    u16* dst = g == 0 ? o0 : (g == 1 ? o1 : (g == 2 ? o2 : o3));
    int i = (blockIdx.x & 511) * 256 + threadIdx.x;
    const float4* s = (const float4*)src;
    float4 a = s[2 * i], b = s[2 * i + 1];
    uint4 o;
    o.x = pk2(a.x, a.y); o.y = pk2(a.z, a.w);
    o.z = pk2(b.x, b.y); o.w = pk2(b.z, b.w);
    ((uint4*)dst)[i] = o;
}

// ---------------------------------------------------- fused QKV GEMM, 2-phase dbuf
// C[M,N] = A[M,K]*W[N,K]^T for 3 weight matrices. M=8192, N=1024 each, K=1024.
// grid (24, 64): blockIdx.x>>3 selects projection. 128x128 tile, BK=64, dbuf LDS.
// Output scatters bf16 to [B,H,S,Dh].
__global__ __launch_bounds__(256) void gemm_qkv(const u16* __restrict__ A,
                                                const u16* __restrict__ W0,
                                                const u16* __restrict__ W1,
                                                const u16* __restrict__ W2,
                                                const float* __restrict__ b0,
                                                const float* __restrict__ b1,
                                                const float* __restrict__ b2,
                                                u16* __restrict__ o0,
                                                u16* __restrict__ o1,
                                                u16* __restrict__ o2) {
    __shared__ u16 Asm[2][128 * 64];
    __shared__ u16 Bsm[2][128 * 64];
    const int tid = threadIdx.x, lane = tid & 63, wave = tid >> 6;
    const int proj = blockIdx.x >> 3;
    const u16* Bw = proj == 0 ? W0 : (proj == 1 ? W1 : W2);
    const float* bias = proj == 0 ? b0 : (proj == 1 ? b1 : b2);
    u16* obf = proj == 0 ? o0 : (proj == 1 ? o1 : o2);
    const int m0 = blockIdx.y * 128, n0 = (blockIdx.x & 7) * 128;
    const int wr = wave >> 1, wc = wave & 1;
    const int srow = lane >> 3;
    const int scol = (lane & 7) ^ srow;
    f32x4 acc[4][4] = {};

    auto STAGE = [&](int bi, int kt) {
#pragma unroll
        for (int i = 0; i < 4; ++i) {
            int ch = wave * 4 + i;
            int r = ch * 8 + srow;
            GLD16(A + (size_t)(m0 + r) * 1024 + kt * 64 + scol * 8, Asm[bi] + ch * 512);
            GLD16(Bw + (size_t)(n0 + r) * 1024 + kt * 64 + scol * 8, Bsm[bi] + ch * 512);
        }
    };

    STAGE(0, 0);
    asm volatile("s_waitcnt vmcnt(0)" ::: "memory");
    __syncthreads();

    for (int kt = 0; kt < 16; ++kt) {
        const int cur = kt & 1;
        if (kt < 15) STAGE(cur ^ 1, kt + 1);
#pragma unroll
        for (int ks = 0; ks < 2; ++ks) {
            bf16x8 af[4], bf[4];
#pragma unroll
            for (int t = 0; t < 4; ++t) {
                int ra = wr * 64 + t * 16 + (lane & 15);
                int ca = (ks * 4 + (lane >> 4)) ^ (ra & 7);
                af[t] = *(const bf16x8*)(Asm[cur] + ra * 64 + ca * 8);
                int rb = wc * 64 + t * 16 + (lane & 15);
                int cb = (ks * 4 + (lane >> 4)) ^ (rb & 7);
                bf[t] = *(const bf16x8*)(Bsm[cur] + rb * 64 + cb * 8);
            }
#pragma unroll
            for (int mi = 0; mi < 4; ++mi)
#pragma unroll
                for (int ni = 0; ni < 4; ++ni)
                    acc[mi][ni] = __builtin_amdgcn_mfma_f32_16x16x32_bf16(
                        af[mi], bf[ni], acc[mi][ni], 0, 0, 0);
        }
        asm volatile("s_waitcnt vmcnt(0)" ::: "memory");
        __syncthreads();
    }

    const int rl = (lane >> 4) * 4, cl = lane & 15;
#pragma unroll
    for (int ni = 0; ni < 4; ++ni) {
        int gn = n0 + wc * 64 + ni * 16 + cl;
        float bv = bias[gn];
        int h = gn >> 6, d = gn & 63;
#pragma unroll
        for (int mi = 0; mi < 4; ++mi) {
#pragma unroll
            for (int r = 0; r < 4; ++r) {
                int gm = m0 + wr * 64 + mi * 16 + rl + r;
                float v = acc[mi][ni][r] + bv;
                int b = gm >> 11, s = gm & 2047;
                obf[(((size_t)(b * 16 + h)) * 2048 + s) * 64 + d] = f2bf(v);
            }
        }
    }
}

// ----------------------------------- O-projection GEMM (single-buffer control)
__global__ __launch_bounds__(256) void gemm_bt(const u16* __restrict__ A,
                                               const u16* __restrict__ Bw,
                                               const float* __restrict__ bias,
                                               float* __restrict__ of32) {
    __shared__ u16 Asm[128 * 64];
    __shared__ u16 Bsm[128 * 64];
    const int tid = threadIdx.x, lane = tid & 63, wave = tid >> 6;
    const int m0 = blockIdx.y * 128, n0 = blockIdx.x * 128;
    const int wr = wave >> 1, wc = wave & 1;
    const int srow = lane >> 3;
    const int scol = (lane & 7) ^ srow;
    f32x4 acc[4][4] = {};

    for (int kt = 0; kt < 16; ++kt) {
        __syncthreads();
#pragma unroll
        for (int i = 0; i < 4; ++i) {
            int ch = wave * 4 + i;
            int r = ch * 8 + srow;
            GLD16(A + (size_t)(m0 + r) * 1024 + kt * 64 + scol * 8, Asm + ch * 512);
            GLD16(Bw + (size_t)(n0 + r) * 1024 + kt * 64 + scol * 8, Bsm + ch * 512);
        }
        asm volatile("s_waitcnt vmcnt(0)" ::: "memory");
        __syncthreads();
#pragma unroll
        for (int ks = 0; ks < 2; ++ks) {
            bf16x8 af[4], bf[4];
#pragma unroll
            for (int t = 0; t < 4; ++t) {
                int ra = wr * 64 + t * 16 + (lane & 15);
                int ca = (ks * 4 + (lane >> 4)) ^ (ra & 7);
                af[t] = *(const bf16x8*)(Asm + ra * 64 + ca * 8);
                int rb = wc * 64 + t * 16 + (lane & 15);
                int cb = (ks * 4 + (lane >> 4)) ^ (rb & 7);
                bf[t] = *(const bf16x8*)(Bsm + rb * 64 + cb * 8);
            }
#pragma unroll
            for (int mi = 0; mi < 4; ++mi)
#pragma unroll
                for (int ni = 0; ni < 4; ++ni)
                    acc[mi][ni] = __builtin_amdgcn_mfma_f32_16x16x32_bf16(
                        af[mi], bf[ni], acc[mi][ni], 0, 0, 0);
        }
    }
    const int rl = (lane >> 4) * 4, cl = lane & 15;
#pragma unroll
    for (int ni = 0; ni < 4; ++ni) {
        int gn = n0 + wc * 64 + ni * 16 + cl;
        float bv = bias[gn];
#pragma unroll
        for (int mi = 0; mi < 4; ++mi) {
#pragma unroll
            for (int r = 0; r < 4; ++r) {
                int gm = m0 + wr * 64 + mi * 16 + rl + r;
                of32[(size_t)gm * 1024 + gn] = acc[mi][ni][r] + bv;
            }
        }
    }
}

// ----------------------------------------- V [BH][S][64] -> VT [BH][64][S]
__global__ __launch_bounds__(256) void vtrans(const u16* __restrict__ V,
                                              u16* __restrict__ VT) {
    __shared__ u16 t[64 * 72];
    const int bh = blockIdx.y, s0 = blockIdx.x * 64;
    const int tid = threadIdx.x;
    const u16* src = V + ((size_t)bh * 2048 + s0) * 64;
#pragma unroll
    for (int p = 0; p < 2; ++p) {
        int si = p * 256 + tid;
        int r = si >> 3, sl = si & 7;
        *(uint4*)(t + r * 72 + sl * 8) = *(const uint4*)(src + r * 64 + sl * 8);
    }
    __syncthreads();
    u16* dst = VT + (size_t)bh * 64 * 2048;
#pragma unroll
    for (int p = 0; p < 2; ++p) {
        int sj = p * 256 + tid;
        int d = sj >> 3, os = (sj & 7) * 8;
        u16 tmp[8];
#pragma unroll
        for (int j = 0; j < 8; ++j) tmp[j] = t[(os + j) * 72 + d];
        *(uint4*)(dst + (size_t)d * 2048 + s0 + os) = *(uint4*)tmp;
    }
}

// ------------------------------------------------------------ flash attention
// grid (S/128, B*H), 256 thr, wave = 32 q-rows. KV tile 64, 2-phase double buffer.
// Swapped QK^T (mfma(K,Q)); P->A-frags via permlane32_swap; defer-max rescale.
__global__ __launch_bounds__(256) void attn_fwd(const u16* __restrict__ Q,
                                                const u16* __restrict__ K,
                                                const u16* __restrict__ VT,
                                                u16* __restrict__ ctx) {
    __shared__ u16 Ksm[2][64 * 64];
    __shared__ u16 Vsm[2][64 * 64];
    const int tid = threadIdx.x, lane = tid & 63, wave = tid >> 6;
    const int bh = blockIdx.y;
    const int q0 = blockIdx.x * 128 + wave * 32;
    const int ql = lane & 31, hi = lane >> 5;
    const int srow = lane >> 3, scol = (lane & 7) ^ srow;

    const u16* Qb = Q + ((size_t)bh * 2048 + q0 + ql) * 64 + hi * 8;
    bf16x8 qf[4];
#pragma unroll
    for (int d16 = 0; d16 < 4; ++d16) qf[d16] = *(const bf16x8*)(Qb + d16 * 16);

    const u16* Kb = K + (size_t)bh * 2048 * 64;
    const u16* Vb = VT + (size_t)bh * 64 * 2048;

    f32x16 o0 = {}, o1 = {};
    float m = -1e30f, lsum = 0.f;
    const float C = 0.18033688011112042f;       // log2(e)/sqrt(64)

    auto STAGE = [&](int bi, int kb) {
#pragma unroll
        for (int i = 0; i < 2; ++i) {
            int ch = wave * 2 + i;
            int r = ch * 8 + srow;
            GLD16(Kb + (size_t)(kb + r) * 64 + scol * 8, Ksm[bi] + ch * 512);
            GLD16(Vb + (size_t)r * 2048 + kb + scol * 8, Vsm[bi] + ch * 512);
        }
    };

    STAGE(0, 0);
    asm volatile("s_waitcnt vmcnt(0)" ::: "memory");
    __syncthreads();

    for (int it = 0; it < 32; ++it) {
        const int cur = it & 1;
        if (it < 31) STAGE(cur ^ 1, (it + 1) * 64);

        // QK^T (swapped): sa[t] rows = keys t*32.., cols = q
        f32x16 sa[2] = {};
        __builtin_amdgcn_s_setprio(1);
#pragma unroll
        for (int t = 0; t < 2; ++t)
#pragma unroll
            for (int d16 = 0; d16 < 4; ++d16) {
                int r = t * 32 + ql;
                int c = (d16 * 2 + hi) ^ (r & 7);
                bf16x8 kf = *(const bf16x8*)(Ksm[cur] + r * 64 + c * 8);
                sa[t] = __builtin_amdgcn_mfma_f32_32x32x16_bf16(kf, qf[d16], sa[t], 0, 0, 0);
            }
        __builtin_amdgcn_s_setprio(0);

        // online softmax for q = ql (32 k-vals in-lane; partner lane l^32)
        float tmax = -1e30f;
#pragma unroll
        for (int t = 0; t < 2; ++t)
#pragma unroll
            for (int r = 0; r < 16; ++r) tmax = fmaxf(tmax, sa[t][r]);
        tmax = fmaxf(tmax, __shfl_xor(tmax, 32));

        // defer-max: skip O-rescale while (tmax-m)*C <= 8 (P bounded by 2^8)
        if (!__all((tmax - m) * C <= 8.0f)) {
            float mn = fmaxf(m, tmax);
            float f = exp2f((m - mn) * C);
#pragma unroll
            for (int r = 0; r < 16; ++r) {
                int crow = (r & 3) + 8 * (r >> 2) + 4 * hi;
                float fr = __shfl(f, (lane & 32) + crow);
                o0[r] *= fr; o1[r] *= fr;
            }
            lsum *= f;
            m = mn;
        }

        float p[32]; float ps = 0.f;
#pragma unroll
        for (int t = 0; t < 2; ++t)
#pragma unroll
            for (int r = 0; r < 16; ++r) {
                float e = exp2f((sa[t][r] - m) * C);
                p[t * 16 + r] = e; ps += e;
            }
        ps += __shfl_xor(ps, 32);
        lsum += ps;

        // P -> bf16 A-frags via permlane32_swap, then PV
#pragma unroll
        for (int t = 0; t < 2; ++t) {
            unsigned pkv[8];
#pragma unroll
            for (int i2 = 0; i2 < 8; ++i2)
                pkv[i2] = pk2(p[t * 16 + 2 * i2], p[t * 16 + 2 * i2 + 1]);
            uint2v s0 = __builtin_amdgcn_permlane32_swap(pkv[0], pkv[2], false, false);
            uint2v s1 = __builtin_amdgcn_permlane32_swap(pkv[1], pkv[3], false, false);
            uint2v s2 = __builtin_amdgcn_permlane32_swap(pkv[4], pkv[6], false, false);
            uint2v s3 = __builtin_amdgcn_permlane32_swap(pkv[5], pkv[7], false, false);
            uint4 fr0 = {s0[0], s1[0], s0[1], s1[1]};
            uint4 fr1 = {s2[0], s3[0], s2[1], s3[1]};
            bf16x8 pf[2] = {__builtin_bit_cast(bf16x8, fr0), __builtin_bit_cast(bf16x8, fr1)};
            __builtin_amdgcn_s_setprio(1);
#pragma unroll
            for (int kk = 0; kk < 2; ++kk) {
#pragma unroll
                for (int db = 0; db < 2; ++db) {
                    int dr = db * 32 + ql;
                    int cc = ((t * 2 + kk) * 2 + hi) ^ (dr & 7);
                    bf16x8 vf = *(const bf16x8*)(Vsm[cur] + dr * 64 + cc * 8);
                    if (db == 0)
                        o0 = __builtin_amdgcn_mfma_f32_32x32x16_bf16(pf[kk], vf, o0, 0, 0, 0);
                    else
                        o1 = __builtin_amdgcn_mfma_f32_32x32x16_bf16(pf[kk], vf, o1, 0, 0, 0);
                }
            }
            __builtin_amdgcn_s_setprio(0);
        }

        asm volatile("s_waitcnt vmcnt(0)" ::: "memory");
        __syncthreads();
    }

    // epilogue: ctx[B,S,H*64] bf16
    float linv = 1.0f / lsum;
    const int b = bh >> 4, h = bh & 15;
#pragma unroll
    for (int r = 0; r < 16; ++r) {
        int crow = (r & 3) + 8 * (r >> 2) + 4 * hi;
        float lr = __shfl(linv, (lane & 32) + crow);
        size_t base = ((size_t)b * 2048 + q0 + crow) * 1024 + h * 64;
        ctx[base + ql] = f2bf(o0[r] * lr);
        ctx[base + 32 + ql] = f2bf(o1[r] * lr);
    }
}

// ---------------------------------------------------------------- launcher
extern "C" void kernel_launch(void* const* d_in, const int* in_sizes, int n_in,
                              void* d_out, int out_size, void* d_ws, size_t ws_size,
                              hipStream_t stream) {
    const float* x  = (const float*)d_in[0];
    const float* Wq = (const float*)d_in[1];
    const float* bq = (const float*)d_in[2];
    const float* Wk = (const float*)d_in[3];
    const float* bk = (const float*)d_in[4];
    const float* Wv = (const float*)d_in[5];
    const float* bv = (const float*)d_in[6];
    const float* Wo = (const float*)d_in[7];
    const float* bo = (const float*)d_in[8];
    float* out = (float*)d_out;

    char* ws = (char*)d_ws;
    u16* xb  = (u16*)(ws);                          // 16 MB (reused as ctx)
    u16* wqb = (u16*)(ws + 16777216);
    u16* wkb = (u16*)(ws + 16777216 + 2097152);
    u16* wvb = (u16*)(ws + 16777216 + 2 * 2097152);
    u16* wob = (u16*)(ws + 16777216 + 3 * 2097152);
    u16* qb  = (u16*)(ws + 25165824);
    u16* kb  = (u16*)(ws + 41943040);
    u16* vb  = (u16*)(ws + 58720256);
    u16* vtb = (u16*)(ws + 75497472);
    u16* ctx = xb;                                   // xb dead after V GEMM

    cvt_bf16<<<4096, 256, 0, stream>>>(x, xb, 1048576);
    cvt_bf16_w4<<<2048, 256, 0, stream>>>(Wq, Wk, Wv, Wo, wqb, wkb, wvb, wob);

    gemm_qkv<<<dim3(24, 64), 256, 0, stream>>>(xb, wqb, wkb, wvb, bq, bk, bv, qb, kb, vb);
    vtrans<<<dim3(32, 64), 256, 0, stream>>>(vb, vtb);
    attn_fwd<<<dim3(16, 64), 256, 0, stream>>>(qb, kb, vtb, ctx);
    gemm_bt<<<dim3(8, 64), 256, 0, stream>>>(ctx, wob, bo, out);
}

// Round 3
// 333.454 us; speedup vs baseline: 1.1329x; 1.0684x over previous
//
#include <hip/hip_runtime.h>

typedef unsigned short u16;
typedef __bf16 bf16x8 __attribute__((ext_vector_type(8)));
typedef __bf16 bf16x2 __attribute__((ext_vector_type(2)));
typedef float f32x4 __attribute__((ext_vector_type(4)));
typedef float f32x16 __attribute__((ext_vector_type(16)));
typedef unsigned int uint2v __attribute__((ext_vector_type(2)));

#define DEV static __device__ __forceinline__

DEV u16 f2bf(float f) { __bf16 h = (__bf16)f; return __builtin_bit_cast(u16, h); }
DEV unsigned pk2(float a, float b) {
    bf16x2 t; t[0] = (__bf16)a; t[1] = (__bf16)b;
    return __builtin_bit_cast(unsigned, t);
}

#define GLD16(gp, lp)                                                          \
    __builtin_amdgcn_global_load_lds(                                          \
        (const __attribute__((address_space(1))) void*)(gp),                   \
        (__attribute__((address_space(3))) void*)(lp), 16, 0, 0)

// ---------------------------------------------------------------- fp32->bf16
__global__ void cvt_bf16(const float* __restrict__ src, u16* __restrict__ dst, int n8) {
    int i = blockIdx.x * 256 + threadIdx.x;
    if (i >= n8) return;
    const float4* s = (const float4*)src;
    float4 a = s[2 * i], b = s[2 * i + 1];
    uint4 o;
    o.x = pk2(a.x, a.y); o.y = pk2(a.z, a.w);
    o.z = pk2(b.x, b.y); o.w = pk2(b.z, b.w);
    ((uint4*)dst)[i] = o;
}

__global__ void cvt_bf16_w4(const float* __restrict__ w0, const float* __restrict__ w1,
                            const float* __restrict__ w2, const float* __restrict__ w3,
                            u16* __restrict__ o0, u16* __restrict__ o1,
                            u16* __restrict__ o2, u16* __restrict__ o3) {
    int g = blockIdx.x >> 9;
    const float* src = g == 0 ? w0 : (g == 1 ? w1 : (g == 2 ? w2 : w3));
    u16* dst = g == 0 ? o0 : (g == 1 ? o1 : (g == 2 ? o2 : o3));
    int i = (blockIdx.x & 511) * 256 + threadIdx.x;
    const float4* s = (const float4*)src;
    float4 a = s[2 * i], b = s[2 * i + 1];
    uint4 o;
    o.x = pk2(a.x, a.y); o.y = pk2(a.z, a.w);
    o.z = pk2(b.x, b.y); o.w = pk2(b.z, b.w);
    ((uint4*)dst)[i] = o;
}

// ---------------------------------------------------- fused QKV GEMM, 2-phase dbuf
// C[M,N] = A[M,K]*W[N,K]^T, M=8192, N=1024 x3, K=1024. 128x128 tile, BK=64.
// proj 0 (Q): scaled by log2(e)/sqrt(64), scatter [B,H,S,Dh].
// proj 1 (K): scatter [B,H,S,Dh].  proj 2 (V): scatter TRANSPOSED [BH,Dh,S].
__global__ __launch_bounds__(256) void gemm_qkv(const u16* __restrict__ A,
                                                const u16* __restrict__ W0,
                                                const u16* __restrict__ W1,
                                                const u16* __restrict__ W2,
                                                const float* __restrict__ b0,
                                                const float* __restrict__ b1,
                                                const float* __restrict__ b2,
                                                u16* __restrict__ o0,
                                                u16* __restrict__ o1,
                                                u16* __restrict__ o2) {
    __shared__ u16 Asm[2][128 * 64];
    __shared__ u16 Bsm[2][128 * 64];
    const int tid = threadIdx.x, lane = tid & 63, wave = tid >> 6;
    // XCD-aware bijective swizzle: nwg = 24*64 = 1536, 1536/8 = 192
    const int lin = blockIdx.y * 24 + blockIdx.x;
    const int wg = (lin & 7) * 192 + (lin >> 3);
    const int bx = wg % 24, by = wg / 24;
    const int proj = bx >> 3;
    const u16* Bw = proj == 0 ? W0 : (proj == 1 ? W1 : W2);
    const float* bias = proj == 0 ? b0 : (proj == 1 ? b1 : b2);
    const int m0 = by * 128, n0 = (bx & 7) * 128;
    const int wr = wave >> 1, wc = wave & 1;
    const int srow = lane >> 3;
    const int scol = (lane & 7) ^ srow;
    f32x4 acc[4][4] = {};

    auto STAGE = [&](int bi, int kt) {
#pragma unroll
        for (int i = 0; i < 4; ++i) {
            int ch = wave * 4 + i;
            int r = ch * 8 + srow;
            GLD16(A + (size_t)(m0 + r) * 1024 + kt * 64 + scol * 8, Asm[bi] + ch * 512);
            GLD16(Bw + (size_t)(n0 + r) * 1024 + kt * 64 + scol * 8, Bsm[bi] + ch * 512);
        }
    };

    STAGE(0, 0);
    asm volatile("s_waitcnt vmcnt(0)" ::: "memory");
    __syncthreads();

    for (int kt = 0; kt < 16; ++kt) {
        const int cur = kt & 1;
        if (kt < 15) STAGE(cur ^ 1, kt + 1);
#pragma unroll
        for (int ks = 0; ks < 2; ++ks) {
            bf16x8 af[4], bf[4];
#pragma unroll
            for (int t = 0; t < 4; ++t) {
                int ra = wr * 64 + t * 16 + (lane & 15);
                int ca = (ks * 4 + (lane >> 4)) ^ (ra & 7);
                af[t] = *(const bf16x8*)(Asm[cur] + ra * 64 + ca * 8);
                int rb = wc * 64 + t * 16 + (lane & 15);
                int cb = (ks * 4 + (lane >> 4)) ^ (rb & 7);
                bf[t] = *(const bf16x8*)(Bsm[cur] + rb * 64 + cb * 8);
            }
            __builtin_amdgcn_s_setprio(1);
#pragma unroll
            for (int mi = 0; mi < 4; ++mi)
#pragma unroll
                for (int ni = 0; ni < 4; ++ni)
                    acc[mi][ni] = __builtin_amdgcn_mfma_f32_16x16x32_bf16(
                        af[mi], bf[ni], acc[mi][ni], 0, 0, 0);
            __builtin_amdgcn_s_setprio(0);
        }
        asm volatile("s_waitcnt vmcnt(0)" ::: "memory");
        __syncthreads();
    }

    const int rl = (lane >> 4) * 4, cl = lane & 15;
    const float scale = (proj == 0) ? 0.18033688011112042f : 1.0f;  // log2(e)/8
#pragma unroll
    for (int ni = 0; ni < 4; ++ni) {
        int gn = n0 + wc * 64 + ni * 16 + cl;
        float bv = bias[gn];
        int h = gn >> 6, d = gn & 63;
#pragma unroll
        for (int mi = 0; mi < 4; ++mi) {
            int gm0 = m0 + wr * 64 + mi * 16 + rl;
            int b = gm0 >> 11, s = gm0 & 2047;
            if (proj == 2) {
                // transposed: VT[(b*16+h)*64 + d][s..s+3], packed 8B store
                u16 pk[4];
#pragma unroll
                for (int r = 0; r < 4; ++r) pk[r] = f2bf(acc[mi][ni][r] + bv);
                *(uint2*)(o2 + (((size_t)(b * 16 + h) * 64 + d) * 2048 + s)) =
                    *(uint2*)pk;
            } else {
                u16* obf = proj == 0 ? o0 : o1;
#pragma unroll
                for (int r = 0; r < 4; ++r) {
                    float v = (acc[mi][ni][r] + bv) * scale;
                    obf[(((size_t)(b * 16 + h)) * 2048 + (s + r)) * 64 + d] = f2bf(v);
                }
            }
        }
    }
}

// ----------------------------------- O-projection GEMM (fp32 out)
__global__ __launch_bounds__(256) void gemm_bt(const u16* __restrict__ A,
                                               const u16* __restrict__ Bw,
                                               const float* __restrict__ bias,
                                               float* __restrict__ of32) {
    __shared__ u16 Asm[2][128 * 64];
    __shared__ u16 Bsm[2][128 * 64];
    const int tid = threadIdx.x, lane = tid & 63, wave = tid >> 6;
    // swizzle: nwg = 8*64 = 512, cpx = 64
    const int lin = blockIdx.y * 8 + blockIdx.x;
    const int wg = (lin & 7) * 64 + (lin >> 3);
    const int m0 = (wg / 8) * 128, n0 = (wg % 8) * 128;
    const int wr = wave >> 1, wc = wave & 1;
    const int srow = lane >> 3;
    const int scol = (lane & 7) ^ srow;
    f32x4 acc[4][4] = {};

    auto STAGE = [&](int bi, int kt) {
#pragma unroll
        for (int i = 0; i < 4; ++i) {
            int ch = wave * 4 + i;
            int r = ch * 8 + srow;
            GLD16(A + (size_t)(m0 + r) * 1024 + kt * 64 + scol * 8, Asm[bi] + ch * 512);
            GLD16(Bw + (size_t)(n0 + r) * 1024 + kt * 64 + scol * 8, Bsm[bi] + ch * 512);
        }
    };

    STAGE(0, 0);
    asm volatile("s_waitcnt vmcnt(0)" ::: "memory");
    __syncthreads();

    for (int kt = 0; kt < 16; ++kt) {
        const int cur = kt & 1;
        if (kt < 15) STAGE(cur ^ 1, kt + 1);
#pragma unroll
        for (int ks = 0; ks < 2; ++ks) {
            bf16x8 af[4], bf[4];
#pragma unroll
            for (int t = 0; t < 4; ++t) {
                int ra = wr * 64 + t * 16 + (lane & 15);
                int ca = (ks * 4 + (lane >> 4)) ^ (ra & 7);
                af[t] = *(const bf16x8*)(Asm[cur] + ra * 64 + ca * 8);
                int rb = wc * 64 + t * 16 + (lane & 15);
                int cb = (ks * 4 + (lane >> 4)) ^ (rb & 7);
                bf[t] = *(const bf16x8*)(Bsm[cur] + rb * 64 + cb * 8);
            }
            __builtin_amdgcn_s_setprio(1);
#pragma unroll
            for (int mi = 0; mi < 4; ++mi)
#pragma unroll
                for (int ni = 0; ni < 4; ++ni)
                    acc[mi][ni] = __builtin_amdgcn_mfma_f32_16x16x32_bf16(
                        af[mi], bf[ni], acc[mi][ni], 0, 0, 0);
            __builtin_amdgcn_s_setprio(0);
        }
        asm volatile("s_waitcnt vmcnt(0)" ::: "memory");
        __syncthreads();
    }
    const int rl = (lane >> 4) * 4, cl = lane & 15;
#pragma unroll
    for (int ni = 0; ni < 4; ++ni) {
        int gn = n0 + wc * 64 + ni * 16 + cl;
        float bv = bias[gn];
#pragma unroll
        for (int mi = 0; mi < 4; ++mi) {
#pragma unroll
            for (int r = 0; r < 4; ++r) {
                int gm = m0 + wr * 64 + mi * 16 + rl + r;
                of32[(size_t)gm * 1024 + gn] = acc[mi][ni][r] + bv;
            }
        }
    }
}

// ------------------------------------------------------------ flash attention
// grid (S/128, B*H), 256 thr, wave = 32 q-rows. KV tile 64.
// T15 pipeline: QK^T(t+1) (MFMA, K 3-buf) overlaps softmax(t) (VALU/trans) + PV(t).
// Q pre-scaled by log2(e)/sqrt(64) in projection -> exp2(sa - m) directly.
__global__ __launch_bounds__(256) void attn_fwd(const u16* __restrict__ Q,
                                                const u16* __restrict__ K,
                                                const u16* __restrict__ VT,
                                                u16* __restrict__ ctx) {
    __shared__ u16 Ksm[3][64 * 64];
    __shared__ u16 Vsm[2][64 * 64];
    const int tid = threadIdx.x, lane = tid & 63, wave = tid >> 6;
    // swizzle: nwg = 16*64 = 1024, cpx = 128
    const int lin = blockIdx.y * 16 + blockIdx.x;
    const int wg = (lin & 7) * 128 + (lin >> 3);
    const int bh = wg >> 4;
    const int q0 = (wg & 15) * 128 + wave * 32;
    const int ql = lane & 31, hi = lane >> 5;
    const int srow = lane >> 3, scol = (lane & 7) ^ srow;

    const u16* Qb = Q + ((size_t)bh * 2048 + q0 + ql) * 64 + hi * 8;
    bf16x8 qf[4];
#pragma unroll
    for (int d16 = 0; d16 < 4; ++d16) qf[d16] = *(const bf16x8*)(Qb + d16 * 16);

    const u16* Kb = K + (size_t)bh * 2048 * 64;
    const u16* Vb = VT + (size_t)bh * 64 * 2048;

    f32x16 o0 = {}, o1 = {};
    float m = -1e30f, lsum = 0.f;

    auto STAGE_K = [&](int bi, int kb) {
#pragma unroll
        for (int i = 0; i < 2; ++i) {
            int ch = wave * 2 + i;
            int r = ch * 8 + srow;
            GLD16(Kb + (size_t)(kb + r) * 64 + scol * 8, Ksm[bi] + ch * 512);
        }
    };
    auto STAGE_V = [&](int bi, int kb) {
#pragma unroll
        for (int i = 0; i < 2; ++i) {
            int ch = wave * 2 + i;
            int r = ch * 8 + srow;
            GLD16(Vb + (size_t)r * 2048 + kb + scol * 8, Vsm[bi] + ch * 512);
        }
    };
    auto QKT = [&](const u16* Ks, f32x16& s0, f32x16& s1) {
        __builtin_amdgcn_s_setprio(1);
#pragma unroll
        for (int t = 0; t < 2; ++t)
#pragma unroll
            for (int d16 = 0; d16 < 4; ++d16) {
                int r = t * 32 + ql;
                int c = (d16 * 2 + hi) ^ (r & 7);
                bf16x8 kf = *(const bf16x8*)(Ks + r * 64 + c * 8);
                if (t == 0)
                    s0 = __builtin_amdgcn_mfma_f32_32x32x16_bf16(kf, qf[d16], s0, 0, 0, 0);
                else
                    s1 = __builtin_amdgcn_mfma_f32_32x32x16_bf16(kf, qf[d16], s1, 0, 0, 0);
            }
        __builtin_amdgcn_s_setprio(0);
    };

    // prologue: K0,V0 resident; K1 in flight; sa = QK^T(0)
    STAGE_K(0, 0); STAGE_V(0, 0);
    asm volatile("s_waitcnt vmcnt(0)" ::: "memory");
    __syncthreads();
    STAGE_K(1, 64);
    f32x16 sa0 = {}, sa1 = {};
    QKT(Ksm[0], sa0, sa1);
    asm volatile("s_waitcnt vmcnt(0)" ::: "memory");
    __syncthreads();

    for (int it = 0; it < 32; ++it) {
        // stage K(t+2), V(t+1)
        if (it + 2 < 32) STAGE_K((it + 2) % 3, (it + 2) * 64);
        if (it + 1 < 32) STAGE_V((it + 1) & 1, (it + 1) * 64);

        // QK^T(t+1) — independent MFMA, overlaps softmax(t) below
        f32x16 sn0 = {}, sn1 = {};
        if (it + 1 < 32) QKT(Ksm[(it + 1) % 3], sn0, sn1);

        // --- softmax(t) on sa0/sa1 (tree max) ---
        float mx[16];
#pragma unroll
        for (int r = 0; r < 16; ++r) mx[r] = fmaxf(sa0[r], sa1[r]);
#pragma unroll
        for (int s = 8; s >= 1; s >>= 1)
#pragma unroll
            for (int r = 0; r < s; ++r) mx[r] = fmaxf(mx[r], mx[r + s]);
        float tmax = fmaxf(mx[0], __shfl_xor(mx[0], 32));

        // defer-max: rescale only when max grew by > 8 (log2 units)
        if (!__all(tmax - m <= 8.0f)) {
            float mn = fmaxf(m, tmax);
            float f = exp2f(m - mn);
#pragma unroll
            for (int r = 0; r < 16; ++r) {
                int crow = (r & 3) + 8 * (r >> 2) + 4 * hi;
                float fr = __shfl(f, (lane & 32) + crow);
                o0[r] *= fr; o1[r] *= fr;
            }
            lsum *= f;
            m = mn;
        }

        // exp in place + 4-slot partial sums (short dep chains)
        float s4[4] = {0.f, 0.f, 0.f, 0.f};
#pragma unroll
        for (int r = 0; r < 16; ++r) {
            sa0[r] = exp2f(sa0[r] - m); s4[r & 3] += sa0[r];
        }
#pragma unroll
        for (int r = 0; r < 16; ++r) {
            sa1[r] = exp2f(sa1[r] - m); s4[r & 3] += sa1[r];
        }
        float ps = (s4[0] + s4[1]) + (s4[2] + s4[3]);
        ps += __shfl_xor(ps, 32);
        lsum += ps;

        // P -> bf16 A-frags via permlane32_swap, PV from Vsm[t&1]
#pragma unroll
        for (int t = 0; t < 2; ++t) {
            unsigned pkv[8];
#pragma unroll
            for (int i2 = 0; i2 < 8; ++i2)
                pkv[i2] = t == 0 ? pk2(sa0[2 * i2], sa0[2 * i2 + 1])
                                 : pk2(sa1[2 * i2], sa1[2 * i2 + 1]);
            uint2v w0 = __builtin_amdgcn_permlane32_swap(pkv[0], pkv[2], false, false);
            uint2v w1 = __builtin_amdgcn_permlane32_swap(pkv[1], pkv[3], false, false);
            uint2v w2 = __builtin_amdgcn_permlane32_swap(pkv[4], pkv[6], false, false);
            uint2v w3 = __builtin_amdgcn_permlane32_swap(pkv[5], pkv[7], false, false);
            uint4 fr0 = {w0[0], w1[0], w0[1], w1[1]};
            uint4 fr1 = {w2[0], w3[0], w2[1], w3[1]};
            bf16x8 pf[2] = {__builtin_bit_cast(bf16x8, fr0), __builtin_bit_cast(bf16x8, fr1)};
            __builtin_amdgcn_s_setprio(1);
#pragma unroll
            for (int kk = 0; kk < 2; ++kk) {
#pragma unroll
                for (int db = 0; db < 2; ++db) {
                    int dr = db * 32 + ql;
                    int cc = ((t * 2 + kk) * 2 + hi) ^ (dr & 7);
                    bf16x8 vf = *(const bf16x8*)(Vsm[it & 1] + dr * 64 + cc * 8);
                    if (db == 0)
                        o0 = __builtin_amdgcn_mfma_f32_32x32x16_bf16(pf[kk], vf, o0, 0, 0, 0);
                    else
                        o1 = __builtin_amdgcn_mfma_f32_32x32x16_bf16(pf[kk], vf, o1, 0, 0, 0);
                }
            }
            __builtin_amdgcn_s_setprio(0);
        }

        asm volatile("s_waitcnt vmcnt(0)" ::: "memory");
        __syncthreads();
        sa0 = sn0; sa1 = sn1;
    }

    // epilogue: ctx[B,S,H*64] bf16
    float linv = 1.0f / lsum;
    const int b = bh >> 4, h = bh & 15;
#pragma unroll
    for (int r = 0; r < 16; ++r) {
        int crow = (r & 3) + 8 * (r >> 2) + 4 * hi;
        float lr = __shfl(linv, (lane & 32) + crow);
        size_t base = ((size_t)b * 2048 + q0 + crow) * 1024 + h * 64;
        ctx[base + ql] = f2bf(o0[r] * lr);
        ctx[base + 32 + ql] = f2bf(o1[r] * lr);
    }
}

// ---------------------------------------------------------------- launcher
extern "C" void kernel_launch(void* const* d_in, const int* in_sizes, int n_in,
                              void* d_out, int out_size, void* d_ws, size_t ws_size,
                              hipStream_t stream) {
    const float* x  = (const float*)d_in[0];
    const float* Wq = (const float*)d_in[1];
    const float* bq = (const float*)d_in[2];
    const float* Wk = (const float*)d_in[3];
    const float* bk = (const float*)d_in[4];
    const float* Wv = (const float*)d_in[5];
    const float* bv = (const float*)d_in[6];
    const float* Wo = (const float*)d_in[7];
    const float* bo = (const float*)d_in[8];
    float* out = (float*)d_out;

    char* ws = (char*)d_ws;
    u16* xb  = (u16*)(ws);                          // 16 MB (reused as ctx)
    u16* wqb = (u16*)(ws + 16777216);
    u16* wkb = (u16*)(ws + 16777216 + 2097152);
    u16* wvb = (u16*)(ws + 16777216 + 2 * 2097152);
    u16* wob = (u16*)(ws + 16777216 + 3 * 2097152);
    u16* qb  = (u16*)(ws + 25165824);
    u16* kb  = (u16*)(ws + 41943040);
    u16* vtb = (u16*)(ws + 58720256);               // V written transposed by gemm_qkv
    u16* ctx = xb;                                   // xb dead after QKV GEMM

    cvt_bf16<<<4096, 256, 0, stream>>>(x, xb, 1048576);
    cvt_bf16_w4<<<2048, 256, 0, stream>>>(Wq, Wk, Wv, Wo, wqb, wkb, wvb, wob);

    gemm_qkv<<<dim3(24, 64), 256, 0, stream>>>(xb, wqb, wkb, wvb, bq, bk, bv, qb, kb, vtb);
    attn_fwd<<<dim3(16, 64), 256, 0, stream>>>(qb, kb, vtb, ctx);
    gemm_bt<<<dim3(8, 64), 256, 0, stream>>>(ctx, wob, bo, out);
}